// Round 15
// baseline (102.648 us; speedup 1.0000x reference)
//
#include <hip/hip_runtime.h>
#include <math.h>

// B=65536 rows, N=1024 cols, fp32.
//   t_b = argmax_c target[b,c]  (first-max tie-break)
//   out = mean_b(-log(y[b,t_b]+1e-8)) + sum_{b,c} w[popc(t_b^c)]*y[b,c]/(B*N),  w[p]=(p==0)?0:6^p
// CHAMPION R13 (97.2us): single-row loop, t double-buffered in regs (12 live float4).
// R14 lesson: prefetching y too (16 live) regressed -> keep R13's loop EXACTLY.
// R15 = R13 hot loop byte-identical + atomic epilogue (drop 2nd kernel launch).
// Helper-function formulation is LOAD-BEARING (R10/R11: inlining -> LDS-promote, 142us).

#define B_ROWS 65536
#define N_COLS 1024
#define WAVES_PER_BLOCK 4
#define ROWS_BLOCKS 2048
#define ROWS_THREADS (WAVES_PER_BLOCK * 64)
#define NWAVES (ROWS_BLOCKS * WAVES_PER_BLOCK)  // 8192 waves -> 8 rows/wave
#define ROWS_PER_WAVE 8

__device__ __forceinline__ void amax4(float4 v, int c0, float& bv, int& bi) {
    // ascending-column scan within the lane: strict > gives first-index semantics
    if (v.x > bv) { bv = v.x; bi = c0;     }
    if (v.y > bv) { bv = v.y; bi = c0 + 1; }
    if (v.z > bv) { bv = v.z; bi = c0 + 2; }
    if (v.w > bv) { bv = v.w; bi = c0 + 3; }
}

__device__ __forceinline__ float wsum4(const float* w_lds, float4 v, int x) {
    // x = t ^ c0 with c0 % 4 == 0, so t^(c0+e) = x^e
    return w_lds[__popc(x)]     * v.x + w_lds[__popc(x ^ 1)] * v.y +
           w_lds[__popc(x ^ 2)] * v.z + w_lds[__popc(x ^ 3)] * v.w;
}

__device__ __forceinline__ float pick16(float4 v0, float4 v1, float4 v2, float4 v3, int t) {
    // statically-indexed select (t>>8 -> which float4 within owning lane, t&3 -> component)
    const int k = (t >> 2) >> 6;   // 0..3
    const int e = t & 3;
    float4 s = (k & 2) ? ((k & 1) ? v3 : v2) : ((k & 1) ? v1 : v0);
    return (e & 2) ? ((e & 1) ? s.w : s.z) : ((e & 1) ? s.y : s.x);
}

__global__ __launch_bounds__(ROWS_THREADS)
void ce_rows_kernel(const float* __restrict__ y_true,
                    const float* __restrict__ target,
                    float* __restrict__ out) {
    __shared__ float w_lds[16];
    __shared__ float wave_part[WAVES_PER_BLOCK];

    const int tid = threadIdx.x;
    if (tid < 16) {
        float w = 1.0f;
        for (int p = 0; p < tid; ++p) w *= 6.0f;   // exact: 6^10 < 2^26
        w_lds[tid] = (tid == 0) ? 0.0f : w;
    }
    __syncthreads();

    const int lane  = tid & 63;
    const int wid   = tid >> 6;
    const int gwave = blockIdx.x * WAVES_PER_BLOCK + wid;

    float acc_pt = 0.0f;   // lane-private weighted-sum partial (unscaled)
    float acc_lg = 0.0f;   // lane-private sum of log(y[t]+1e-8) (owner lanes only)

    // prologue: target row for s=0 into the current buffer
    const float4* tp0 = (const float4*)(target + (size_t)gwave * N_COLS);
    float4 tc0 = tp0[lane], tc1 = tp0[lane + 64], tc2 = tp0[lane + 128], tc3 = tp0[lane + 192];

    #pragma unroll 1
    for (int s = 0; s < ROWS_PER_WAVE; ++s) {
        const int row = gwave + s * NWAVES;

        // issue y(row) loads — consumed only after the chain (latency hidden)
        const float4* yp = (const float4*)(y_true + (size_t)row * N_COLS);
        float4 y0 = yp[lane], y1 = yp[lane + 64], y2 = yp[lane + 128], y3 = yp[lane + 192];

        // issue t(row+NWAVES) prefetch — consumed next iteration (fully hidden)
        float4 tn0 = tc0, tn1 = tc1, tn2 = tc2, tn3 = tc3;
        if (s < ROWS_PER_WAVE - 1) {   // wave-uniform branch
            const float4* tn = (const float4*)(target + (size_t)(row + NWAVES) * N_COLS);
            tn0 = tn[lane]; tn1 = tn[lane + 64]; tn2 = tn[lane + 128]; tn3 = tn[lane + 192];
        }

        // local argmax on resident t (no memory wait); strict > = first-index
        float bv = -1.0f; int bi = 0;
        amax4(tc0, 4 * lane,         bv, bi);
        amax4(tc1, 4 * (lane + 64),  bv, bi);
        amax4(tc2, 4 * (lane + 128), bv, bi);
        amax4(tc3, 4 * (lane + 192), bv, bi);

        // cross-lane argmax with first-index tie-break; y/t-next stream in underneath
        #pragma unroll
        for (int m = 32; m >= 1; m >>= 1) {
            const float ov = __shfl_xor(bv, m, 64);
            const int   oi = __shfl_xor(bi, m, 64);
            if (ov > bv || (ov == bv && oi < bi)) { bv = ov; bi = oi; }
        }
        const int t = bi;   // wave-uniform

        // weighted sum: lane-private, no per-row reduction (popc(t^t)=0 -> w=0)
        acc_pt += wsum4(w_lds, y0, t ^ (4 * lane))
                + wsum4(w_lds, y1, t ^ (4 * (lane + 64)))
                + wsum4(w_lds, y2, t ^ (4 * (lane + 128)))
                + wsum4(w_lds, y3, t ^ (4 * (lane + 192)));

        // CE term: only the lane owning column t computes the log
        if (((t >> 2) & 63) == lane)
            acc_lg += logf(pick16(y0, y1, y2, y3, t) + 1e-8f);

        // rotate the double buffer
        tc0 = tn0; tc1 = tn1; tc2 = tn2; tc3 = tn3;
    }

    // single per-wave reduction at the end
    const float invB  = 1.0f / (float)B_ROWS;
    const float invBN = 1.0f / ((float)B_ROWS * (float)N_COLS);
    float val = acc_pt * invBN - acc_lg * invB;
    #pragma unroll
    for (int m = 32; m >= 1; m >>= 1) val += __shfl_xor(val, m, 64);

    if (lane == 0) wave_part[wid] = val;
    __syncthreads();
    if (tid == 0) {
        float s = 0.0f;
        #pragma unroll
        for (int w = 0; w < WAVES_PER_BLOCK; ++w) s += wave_part[w];
        atomicAdd(out, s);   // 2048 adds; reorder noise ~1e-3 << threshold 2764
    }
}

extern "C" void kernel_launch(void* const* d_in, const int* in_sizes, int n_in,
                              void* d_out, int out_size, void* d_ws, size_t ws_size,
                              hipStream_t stream) {
    const float* y_true = (const float*)d_in[0];
    const float* target = (const float*)d_in[1];
    float* out = (float*)d_out;

    hipMemsetAsync(out, 0, sizeof(float), stream);
    ce_rows_kernel<<<ROWS_BLOCKS, ROWS_THREADS, 0, stream>>>(y_true, target, out);
}

// Round 16
// 97.497 us; speedup vs baseline: 1.0528x; 1.0528x over previous
//
#include <hip/hip_runtime.h>
#include <math.h>

// B=65536 rows, N=1024 cols, fp32.
//   t_b = argmax_c target[b,c]  (first-max tie-break)
//   out = mean_b(-log(y[b,t_b]+1e-8)) + sum_{b,c} w[popc(t_b^c)]*y[b,c]/(B*N),  w[p]=(p==0)?0:6^p
// FINAL CHAMPION (R13, 97.2us = 84% of 6.29 TB/s stream ceiling): single-row loop,
// target row double-buffered in registers one iter ahead; amax waits on nothing; the
// 6-shuffle chain hides y + t-next load latency. Two-kernel finish (atomic regressed, R15).
// Helper-function formulation is LOAD-BEARING (R10/R11: inlining -> LDS-promote, 142us).
// Tried & worse: 4-row batch (spill), y-prefetch too (R14), split kernels (R7),
// NT hints (R8), launch_bounds hints (R6/R10), atomic epilogue (R15).

#define B_ROWS 65536
#define N_COLS 1024
#define WAVES_PER_BLOCK 4
#define ROWS_BLOCKS 2048
#define ROWS_THREADS (WAVES_PER_BLOCK * 64)
#define NWAVES (ROWS_BLOCKS * WAVES_PER_BLOCK)  // 8192 waves -> 8 rows/wave
#define ROWS_PER_WAVE 8

__device__ __forceinline__ void amax4(float4 v, int c0, float& bv, int& bi) {
    // ascending-column scan within the lane: strict > gives first-index semantics
    if (v.x > bv) { bv = v.x; bi = c0;     }
    if (v.y > bv) { bv = v.y; bi = c0 + 1; }
    if (v.z > bv) { bv = v.z; bi = c0 + 2; }
    if (v.w > bv) { bv = v.w; bi = c0 + 3; }
}

__device__ __forceinline__ float wsum4(const float* w_lds, float4 v, int x) {
    // x = t ^ c0 with c0 % 4 == 0, so t^(c0+e) = x^e
    return w_lds[__popc(x)]     * v.x + w_lds[__popc(x ^ 1)] * v.y +
           w_lds[__popc(x ^ 2)] * v.z + w_lds[__popc(x ^ 3)] * v.w;
}

__device__ __forceinline__ float pick16(float4 v0, float4 v1, float4 v2, float4 v3, int t) {
    // statically-indexed select (t>>8 -> which float4 within owning lane, t&3 -> component)
    const int k = (t >> 2) >> 6;   // 0..3
    const int e = t & 3;
    float4 s = (k & 2) ? ((k & 1) ? v3 : v2) : ((k & 1) ? v1 : v0);
    return (e & 2) ? ((e & 1) ? s.w : s.z) : ((e & 1) ? s.y : s.x);
}

__global__ __launch_bounds__(ROWS_THREADS)
void ce_rows_kernel(const float* __restrict__ y_true,
                    const float* __restrict__ target,
                    float* __restrict__ partials) {
    __shared__ float w_lds[16];
    __shared__ float wave_part[WAVES_PER_BLOCK];

    const int tid = threadIdx.x;
    if (tid < 16) {
        float w = 1.0f;
        for (int p = 0; p < tid; ++p) w *= 6.0f;   // exact: 6^10 < 2^26
        w_lds[tid] = (tid == 0) ? 0.0f : w;
    }
    __syncthreads();

    const int lane  = tid & 63;
    const int wid   = tid >> 6;
    const int gwave = blockIdx.x * WAVES_PER_BLOCK + wid;

    float acc_pt = 0.0f;   // lane-private weighted-sum partial (unscaled)
    float acc_lg = 0.0f;   // lane-private sum of log(y[t]+1e-8) (owner lanes only)

    // prologue: target row for s=0 into the current buffer
    const float4* tp0 = (const float4*)(target + (size_t)gwave * N_COLS);
    float4 tc0 = tp0[lane], tc1 = tp0[lane + 64], tc2 = tp0[lane + 128], tc3 = tp0[lane + 192];

    #pragma unroll 1
    for (int s = 0; s < ROWS_PER_WAVE; ++s) {
        const int row = gwave + s * NWAVES;

        // issue y(row) loads — consumed only after the chain (latency hidden)
        const float4* yp = (const float4*)(y_true + (size_t)row * N_COLS);
        float4 y0 = yp[lane], y1 = yp[lane + 64], y2 = yp[lane + 128], y3 = yp[lane + 192];

        // issue t(row+NWAVES) prefetch — consumed next iteration (fully hidden)
        float4 tn0 = tc0, tn1 = tc1, tn2 = tc2, tn3 = tc3;
        if (s < ROWS_PER_WAVE - 1) {   // wave-uniform branch
            const float4* tn = (const float4*)(target + (size_t)(row + NWAVES) * N_COLS);
            tn0 = tn[lane]; tn1 = tn[lane + 64]; tn2 = tn[lane + 128]; tn3 = tn[lane + 192];
        }

        // local argmax on resident t (no memory wait); strict > = first-index
        float bv = -1.0f; int bi = 0;
        amax4(tc0, 4 * lane,         bv, bi);
        amax4(tc1, 4 * (lane + 64),  bv, bi);
        amax4(tc2, 4 * (lane + 128), bv, bi);
        amax4(tc3, 4 * (lane + 192), bv, bi);

        // cross-lane argmax with first-index tie-break; y/t-next stream in underneath
        #pragma unroll
        for (int m = 32; m >= 1; m >>= 1) {
            const float ov = __shfl_xor(bv, m, 64);
            const int   oi = __shfl_xor(bi, m, 64);
            if (ov > bv || (ov == bv && oi < bi)) { bv = ov; bi = oi; }
        }
        const int t = bi;   // wave-uniform

        // weighted sum: lane-private, no per-row reduction (popc(t^t)=0 -> w=0)
        acc_pt += wsum4(w_lds, y0, t ^ (4 * lane))
                + wsum4(w_lds, y1, t ^ (4 * (lane + 64)))
                + wsum4(w_lds, y2, t ^ (4 * (lane + 128)))
                + wsum4(w_lds, y3, t ^ (4 * (lane + 192)));

        // CE term: only the lane owning column t computes the log
        if (((t >> 2) & 63) == lane)
            acc_lg += logf(pick16(y0, y1, y2, y3, t) + 1e-8f);

        // rotate the double buffer
        tc0 = tn0; tc1 = tn1; tc2 = tn2; tc3 = tn3;
    }

    // single per-wave reduction at the end
    const float invB  = 1.0f / (float)B_ROWS;
    const float invBN = 1.0f / ((float)B_ROWS * (float)N_COLS);
    float val = acc_pt * invBN - acc_lg * invB;
    #pragma unroll
    for (int m = 32; m >= 1; m >>= 1) val += __shfl_xor(val, m, 64);

    if (lane == 0) wave_part[wid] = val;
    __syncthreads();
    if (tid == 0) {
        float s = 0.0f;
        #pragma unroll
        for (int w = 0; w < WAVES_PER_BLOCK; ++w) s += wave_part[w];
        partials[blockIdx.x] = s;
    }
}

__global__ __launch_bounds__(256)
void ce_reduce_kernel(const float* __restrict__ partials, int n, float* __restrict__ out) {
    __shared__ float s[256];
    const int tid = threadIdx.x;
    float a = 0.0f;
    for (int i = tid; i < n; i += 256) a += partials[i];  // fixed order -> deterministic
    s[tid] = a;
    __syncthreads();
    for (int off = 128; off > 0; off >>= 1) {
        if (tid < off) s[tid] += s[tid + off];
        __syncthreads();
    }
    if (tid == 0) out[0] = s[0];
}

extern "C" void kernel_launch(void* const* d_in, const int* in_sizes, int n_in,
                              void* d_out, int out_size, void* d_ws, size_t ws_size,
                              hipStream_t stream) {
    const float* y_true = (const float*)d_in[0];
    const float* target = (const float*)d_in[1];
    float* out = (float*)d_out;
    float* partials = (float*)d_ws;  // ROWS_BLOCKS floats = 8 KB

    ce_rows_kernel<<<ROWS_BLOCKS, ROWS_THREADS, 0, stream>>>(y_true, target, partials);
    ce_reduce_kernel<<<1, 256, 0, stream>>>(partials, ROWS_BLOCKS, out);
}